// Round 18
// baseline (2766.954 us; speedup 1.0000x reference)
//
#include <hip/hip_runtime.h>
#include <hip/hip_fp16.h>

#define NN 50000
#define EE 800000
#define ETOT 850000
#define KIN 61
#define HH 256
#define NH 8
#define CC 32
#define LL 4
#define SCAN_NBLK 49   // ceil(NN/1024)

typedef __attribute__((ext_vector_type(8))) short bf16x8;
typedef __attribute__((ext_vector_type(4))) float f32x4;

__device__ __forceinline__ unsigned short f2b(float f) {
    unsigned u = __builtin_bit_cast(unsigned, f);
    u += 0x7fffu + ((u >> 16) & 1u);   // RNE
    return (unsigned short)(u >> 16);
}
__device__ __forceinline__ float b2f(unsigned short h) {
    unsigned u = ((unsigned)h) << 16;
    return __builtin_bit_cast(float, u);
}
__device__ __forceinline__ unsigned short f2h(float f) {
    __half h = __float2half(f);        // RNE
    return __builtin_bit_cast(unsigned short, h);
}

// async global->LDS, 16B per lane; LDS dest is wave-uniform base + lane*16
__device__ __forceinline__ void gload16(const void* g, void* l) {
    __builtin_amdgcn_global_load_lds(
        (const __attribute__((address_space(1))) void*)g,
        (__attribute__((address_space(3))) void*)l, 16, 0, 0);
}

// ============================ CSR build ============================

__global__ __launch_bounds__(256) void edge_hist(const int* __restrict__ ei,
                                                 int* __restrict__ counts) {
    int e = blockIdx.x * 256 + threadIdx.x;
    if (e >= ETOT) return;
    int d = (e < EE) ? ei[EE + e] : (e - EE);
    atomicAdd(&counts[d], 1);
}

__global__ __launch_bounds__(256) void scan1(const int* __restrict__ counts,
                                             int* __restrict__ tmp,
                                             int* __restrict__ bsums) {
    __shared__ int lds[256];
    int b = blockIdx.x, t = threadIdx.x;
    int base = b * 1024 + t * 4;
    int v0 = 0, v1 = 0, v2 = 0, v3 = 0;
    if (base + 0 < NN) v0 = counts[base + 0];
    if (base + 1 < NN) v1 = counts[base + 1];
    if (base + 2 < NN) v2 = counts[base + 2];
    if (base + 3 < NN) v3 = counts[base + 3];
    int s = v0 + v1 + v2 + v3;
    lds[t] = s;
    __syncthreads();
    for (int off = 1; off < 256; off <<= 1) {
        int x = (t >= off) ? lds[t - off] : 0;
        __syncthreads();
        lds[t] += x;
        __syncthreads();
    }
    int run = lds[t] - s;
    if (t == 255) bsums[b] = lds[255];
    run += v0; if (base + 0 < NN) tmp[base + 0] = run;
    run += v1; if (base + 1 < NN) tmp[base + 1] = run;
    run += v2; if (base + 2 < NN) tmp[base + 2] = run;
    run += v3; if (base + 3 < NN) tmp[base + 3] = run;
}

// wave-parallel exclusive prefix over SCAN_NBLK block sums (1 wave)
__global__ void scan2(int* __restrict__ bsums) {
    int lane = threadIdx.x;                       // 64 threads
    int v = (lane < SCAN_NBLK) ? bsums[lane] : 0;
    int inc = v;
    for (int off = 1; off < 64; off <<= 1) {
        int t = __shfl_up(inc, off);
        if (lane >= off) inc += t;
    }
    if (lane < SCAN_NBLK) bsums[lane] = inc - v;  // exclusive
}

__global__ __launch_bounds__(256) void scan3(const int* __restrict__ tmp,
                                             const int* __restrict__ bsums,
                                             const int* __restrict__ counts,
                                             int* __restrict__ rowptr,
                                             int* __restrict__ cursor) {
    int i = blockIdx.x * 256 + threadIdx.x;
    if (i >= NN) return;
    int incl = tmp[i] + bsums[i >> 10];
    rowptr[i + 1] = incl;
    cursor[i] = incl - counts[i];
    if (i == 0) rowptr[0] = 0;
}

__global__ __launch_bounds__(256) void edge_scatter(const int* __restrict__ ei,
                                                    int* __restrict__ cursor,
                                                    int* __restrict__ ssrc) {
    int e = blockIdx.x * 256 + threadIdx.x;
    if (e >= ETOT) return;
    int s, d;
    if (e < EE) { s = ei[e]; d = ei[EE + e]; } else { s = d = e - EE; }
    int pos = atomicAdd(&cursor[d], 1);
    ssrc[pos] = s;
}

// sort each row's sources ascending (deterministic 64-lane bitonic).
__global__ __launch_bounds__(256) void sort_rows(const int* __restrict__ rowptr,
                                                 int* __restrict__ ssrc) {
    int wid = (blockIdx.x * 256 + threadIdx.x) >> 6;
    int lane = threadIdx.x & 63;
    if (wid >= NN) return;
    int beg = rowptr[wid], end = rowptr[wid + 1];
    int L = end - beg;
    if (L > 64) return;
    int v = (lane < L) ? ssrc[beg + lane] : 0x7fffffff;
#pragma unroll
    for (int k = 2; k <= 64; k <<= 1) {
#pragma unroll
        for (int j = k >> 1; j > 0; j >>= 1) {
            int partner = __shfl_xor(v, j);
            bool up = ((lane & k) == 0);
            bool keepMin = (up == ((lane & j) == 0));
            int mn = min(v, partner), mx = max(v, partner);
            v = keepMin ? mn : mx;
        }
    }
    if (lane < L) ssrc[beg + lane] = v;
}

// ============================ weight / input prep (bf16) ============================

__global__ __launch_bounds__(256) void prep_wt(const float* __restrict__ Ws,
                                               unsigned short* __restrict__ WT) {
    int t = blockIdx.x * 256 + threadIdx.x;
    if (t >= LL * HH * HH) return;
    int l = t >> 16, rem = t & 65535;
    int n = rem >> 8, k = rem & 255;
    WT[t] = f2b(Ws[l * 65536 + k * HH + n]);
}

// WaT[l][oc][k] = bf16( sum_c W[k][hd*32+c] * a[hd][c] ), oc<8: att_src, else att_dst.
__global__ __launch_bounds__(256) void prep_wa(const float* __restrict__ Ws,
                                               const float* __restrict__ att_src,
                                               const float* __restrict__ att_dst,
                                               unsigned short* __restrict__ WaT) {
    int t = blockIdx.x * 256 + threadIdx.x;
    if (t >= LL * 16 * 256) return;
    int l = t >> 12, rem = t & 4095;
    int oc = rem >> 8, k = rem & 255;
    int hd = oc & 7;
    const float* a = ((oc < 8) ? att_src : att_dst) + ((size_t)l * NH + hd) * CC;
    const float* Wl = Ws + (size_t)l * 65536 + (size_t)k * HH + hd * CC;
    float s = 0.f;
#pragma unroll
    for (int c = 0; c < CC; ++c) s += Wl[c] * a[c];
    WaT[t] = f2b(s);
}

__global__ __launch_bounds__(256) void prep_inwt(const float* __restrict__ in_W,
                                                 unsigned short* __restrict__ WT) {
    int t = blockIdx.x * 256 + threadIdx.x;
    if (t >= HH * 64) return;
    int n = t >> 6, k = t & 63;
    WT[t] = (k < KIN) ? f2b(in_W[k * HH + n]) : 0;
}

__global__ __launch_bounds__(256) void prep_x(const float* __restrict__ x,
                                              unsigned short* __restrict__ xb) {
    int t = blockIdx.x * 256 + threadIdx.x;
    if (t >= NN * 64) return;
    int n = t >> 6, c = t & 63;
    xb[t] = (c < KIN) ? f2b(x[n * KIN + c]) : 0;
}

// ============================ MFMA GEMM (+ fused BN + attn-score columns) ============================
// tile 128 rows x 256(+16) cols x 64 K, 8 waves (512 thr) arranged 2(wm) x 4(wn).
// MODE 0: A via gload16, C row-major bf16 + fused column stats (atomicAdd sums).
// MODE 1: A = relu(bn(bnX)) [+res] built during staging (also written to hbNew);
//   C = row-major f16 z; Bs rows 256..271 hold WaT -> waves wn==0 compute the
//   16 es|ed score columns (accX) and store them node-major esed[n][16]
//   (64 B coalesced per q-group). No cross-lane reduction.
// BOTH: zero zsums (next stage's stats buffer) -- deletes memset dispatches.
template<int MODE>
__global__ __launch_bounds__(512) void gemm_mfma(const unsigned short* __restrict__ Asrc,
                                                 const unsigned short* __restrict__ Bt,
                                                 const unsigned short* __restrict__ WaTl,
                                                 unsigned short* __restrict__ C,
                                                 float* __restrict__ esed,
                                                 float* __restrict__ sums,
                                                 float* __restrict__ zsums,
                                                 const float* __restrict__ gamma,
                                                 const float* __restrict__ beta,
                                                 const unsigned short* __restrict__ res,
                                                 unsigned short* __restrict__ hbNew,
                                                 int M, int K) {
    __shared__ unsigned short As[128 * 64];   // 16 KB
    __shared__ unsigned short Bs[272 * 64];   // 34 KB (rows 256..271 = Wa cols)
    __shared__ float scaleS[256], shiftS[256];
    int row0 = blockIdx.x * 128;
    int tid = threadIdx.x;
    int w = tid >> 6, l = tid & 63;
    int wm = w >> 2, wn = w & 3;
    int r15 = l & 15, q = l >> 4;

    if (tid < 256) {                      // all blocks write 0: idempotent
        zsums[tid] = 0.f;
        zsums[HH + tid] = 0.f;
    }
    if constexpr (MODE == 1) {
        if (tid < 256) {
            const float invN = 1.f / NN;
            float mn = sums[tid] * invN;
            float var = fmaxf(sums[256 + tid] * invN - mn * mn, 0.f);
            float rs = rsqrtf(var + 1e-5f);
            float sc = rs * gamma[tid];
            scaleS[tid] = sc;
            shiftS[tid] = beta[tid] - mn * sc;
        }
        __syncthreads();
    }

    f32x4 acc[4][4] = {};
    f32x4 accX[4] = {};          // es/ed columns (used by wn==0 waves)

    int crow = l >> 3;     // row within 8-row chunk
    int cs   = l & 7;      // 16B slot within row

    for (int kt = 0; kt < K; kt += 64) {
        if (kt) __syncthreads();
        // stage A: wave w covers rows w*16 .. w*16+15 (2 chunks of 8)
#pragma unroll
        for (int c = 0; c < 2; ++c) {
            int r = w * 16 + c * 8 + crow;          // 0..127
            int sg = cs ^ (r & 7);                  // pre-swizzled source slot
            int ga = row0 + r;
            if constexpr (MODE == 0) {
                if (ga >= M) ga = M - 1;
                gload16(&Asrc[(size_t)ga * K + kt + sg * 8], &As[(w * 16 + c * 8) * 64]);
            } else {
                unsigned short* dst = &As[(w * 16 + c * 8) * 64 + l * 8];
                if (ga < M) {
                    int ch = kt + sg * 8;
                    ushort4 xlo = *(const ushort4*)&Asrc[(size_t)ga * 256 + ch];
                    ushort4 xhi = *(const ushort4*)&Asrc[(size_t)ga * 256 + ch + 4];
                    float4 sc0 = *(const float4*)&scaleS[ch];
                    float4 sc1 = *(const float4*)&scaleS[ch + 4];
                    float4 sh0 = *(const float4*)&shiftS[ch];
                    float4 sh1 = *(const float4*)&shiftS[ch + 4];
                    float f0 = fmaxf(b2f(xlo.x) * sc0.x + sh0.x, 0.f);
                    float f1 = fmaxf(b2f(xlo.y) * sc0.y + sh0.y, 0.f);
                    float f2 = fmaxf(b2f(xlo.z) * sc0.z + sh0.z, 0.f);
                    float f3 = fmaxf(b2f(xlo.w) * sc0.w + sh0.w, 0.f);
                    float f4 = fmaxf(b2f(xhi.x) * sc1.x + sh1.x, 0.f);
                    float f5 = fmaxf(b2f(xhi.y) * sc1.y + sh1.y, 0.f);
                    float f6 = fmaxf(b2f(xhi.z) * sc1.z + sh1.z, 0.f);
                    float f7 = fmaxf(b2f(xhi.w) * sc1.w + sh1.w, 0.f);
                    if (res) {
                        ushort4 rlo = *(const ushort4*)&res[(size_t)ga * 256 + ch];
                        ushort4 rhi = *(const ushort4*)&res[(size_t)ga * 256 + ch + 4];
                        f0 += b2f(rlo.x); f1 += b2f(rlo.y); f2 += b2f(rlo.z); f3 += b2f(rlo.w);
                        f4 += b2f(rhi.x); f5 += b2f(rhi.y); f6 += b2f(rhi.z); f7 += b2f(rhi.w);
                    }
                    ushort4 olo, ohi;
                    olo.x = f2b(f0); olo.y = f2b(f1); olo.z = f2b(f2); olo.w = f2b(f3);
                    ohi.x = f2b(f4); ohi.y = f2b(f5); ohi.z = f2b(f6); ohi.w = f2b(f7);
                    *(ushort4*)dst = olo;
                    *(ushort4*)(dst + 4) = ohi;
                    *(ushort4*)&hbNew[(size_t)ga * 256 + ch] = olo;
                    *(ushort4*)&hbNew[(size_t)ga * 256 + ch + 4] = ohi;
                } else {
                    ushort4 zz = {0, 0, 0, 0};
                    *(ushort4*)dst = zz;
                    *(ushort4*)(dst + 4) = zz;
                }
            }
        }
        // stage B: wave w stages rows w*32 .. w*32+31 (4 chunks of 8)
#pragma unroll
        for (int c = 0; c < 4; ++c) {
            int r = w * 32 + c * 8 + crow;          // 0..255
            int sg = cs ^ (r & 7);
            gload16(&Bt[(size_t)r * K + kt + sg * 8], &Bs[(w * 32 + c * 8) * 64]);
        }
        if constexpr (MODE == 1) {
            // stage Wa rows 256..271 (waves 0,1; one 8-row chunk each)
            if (w < 2) {
                int rr = w * 8 + crow;              // 0..15
                int sg = cs ^ (crow & 7);           // (256+rr)&7 == crow
                gload16(&WaTl[(size_t)rr * K + kt + sg * 8], &Bs[(256 + w * 8) * 64]);
            }
        }
        __syncthreads();
#pragma unroll
        for (int kk = 0; kk < 2; ++kk) {
            bf16x8 aF[4], bF[4];
#pragma unroll
            for (int i = 0; i < 4; ++i) {
                int ar = wm * 64 + i * 16 + r15;
                aF[i] = *(bf16x8*)&As[ar * 64 + ((kk * 4 + q) ^ (ar & 7)) * 8];
                int br = wn * 64 + i * 16 + r15;
                bF[i] = *(bf16x8*)&Bs[br * 64 + ((kk * 4 + q) ^ (br & 7)) * 8];
            }
#pragma unroll
            for (int i = 0; i < 4; ++i)
#pragma unroll
                for (int j = 0; j < 4; ++j)
                    acc[i][j] = __builtin_amdgcn_mfma_f32_16x16x32_bf16(aF[i], bF[j], acc[i][j], 0, 0, 0);
            if constexpr (MODE == 1) {
                if (wn == 0) {
                    int br = 256 + r15;
                    bf16x8 bX = *(bf16x8*)&Bs[br * 64 + ((kk * 4 + q) ^ (br & 7)) * 8];
#pragma unroll
                    for (int i = 0; i < 4; ++i)
                        accX[i] = __builtin_amdgcn_mfma_f32_16x16x32_bf16(aF[i], bX, accX[i], 0, 0, 0);
                }
            }
        }
    }

    // C/D layout: col = lane&15, row = (lane>>4)*4 + reg
#pragma unroll
    for (int i = 0; i < 4; ++i)
#pragma unroll
        for (int j = 0; j < 4; ++j) {
            int nc = wn * 64 + j * 16 + r15;
#pragma unroll
            for (int r = 0; r < 4; ++r) {
                int gr = row0 + wm * 64 + i * 16 + q * 4 + r;
                if (gr < M) {
                    if (MODE == 1)
                        C[(size_t)gr * HH + nc] = f2h(acc[i][j][r]);
                    else
                        C[(size_t)gr * HH + nc] = f2b(acc[i][j][r]);
                }
            }
        }

    if constexpr (MODE == 1) {
        // attn scores: accX cols 0..7 = es(head), 8..15 = ed(head).
        // node-major esed[n][16] -> 64 B coalesced store per q-group.
        if (wn == 0) {
#pragma unroll
            for (int i = 0; i < 4; ++i)
#pragma unroll
                for (int r = 0; r < 4; ++r) {
                    int gr = row0 + wm * 64 + i * 16 + q * 4 + r;
                    if (gr < M) esed[(size_t)gr * 16 + r15] = accX[i][r];
                }
        }
    } else {
        // fused column stats over this block's valid rows (rounded values)
#pragma unroll
        for (int j = 0; j < 4; ++j) {
            float v = 0.f, qq = 0.f;
#pragma unroll
            for (int i = 0; i < 4; ++i)
#pragma unroll
                for (int r = 0; r < 4; ++r) {
                    int gr = row0 + wm * 64 + i * 16 + q * 4 + r;
                    if (gr < M) {
                        float f = b2f(f2b(acc[i][j][r]));
                        v += f; qq += f * f;
                    }
                }
            v += __shfl_xor(v, 16); qq += __shfl_xor(qq, 16);
            v += __shfl_xor(v, 32); qq += __shfl_xor(qq, 32);
            if (q == 0) {
                int nc = wn * 64 + j * 16 + r15;
                atomicAdd(&sums[nc], v);
                atomicAdd(&sums[HH + nc], qq);
            }
        }
    }
}

// ============================ aggregate v11 (row-major full-row gather) ============================
// Block = 8 nodes (grid NN/8 exact), 4 waves; wave handles 2 nodes sequentially.
// Phase A: stage (s, p[8]) in LDS: owner via 3-step search; es read as one 32B
// vector esed[s][0..7]; ed from LDS; 8 exps per edge (once, not per lane).
// Phase B: 64 lanes gather the FULL 512B z row per edge (4 cache lines vs 8 in
// the head-split scheme), p broadcast from LDS, f16 banks, 4-unrolled.
// Epilogue: fused column stats. Deterministic (sorted edges, fixed order).
#define MAXEB8 512   // max edges per 8-node block (rows <= 64 each)
__global__ __launch_bounds__(256) void aggregate(const int* __restrict__ rowptr,
                                                 const int* __restrict__ ssrc,
                                                 const float* __restrict__ esed,
                                                 const unsigned short* __restrict__ z,
                                                 unsigned short* __restrict__ outb,
                                                 float* __restrict__ sums) {
    __shared__ int   s_lds[MAXEB8];
    __shared__ float p_lds[MAXEB8 * 8];
    __shared__ int   rp_lds[9];
    __shared__ float ed_lds[8][8];
    __shared__ float ws[4][64][8];
    int n0 = blockIdx.x * 8;
    int tid = threadIdx.x;

    if (tid <= 8) rp_lds[tid] = rowptr[n0 + tid];
    if (tid < 64) ed_lds[tid >> 3][tid & 7] =
        esed[(size_t)(n0 + (tid >> 3)) * 16 + 8 + (tid & 7)];
    __syncthreads();
    int beg0 = rp_lds[0];
    int total = rp_lds[8] - beg0;
    bool staged = (total <= MAXEB8);
    if (staged) {
        for (int j = tid; j < total; j += 256) {
            int jj = beg0 + j;
            int s = ssrc[jj];
            int lo = 0, hi = 8;
#pragma unroll
            for (int st = 0; st < 3; ++st) {
                int mid = (lo + hi) >> 1;
                bool le = (rp_lds[mid] <= jj);
                lo = le ? mid : lo;
                hi = le ? hi : mid;
            }
            float4 ea = *(const float4*)&esed[(size_t)s * 16];
            float4 eb = *(const float4*)&esed[(size_t)s * 16 + 4];
            float es_[8] = {ea.x, ea.y, ea.z, ea.w, eb.x, eb.y, eb.z, eb.w};
            float pv[8];
#pragma unroll
            for (int h = 0; h < 8; ++h) {
                float e = es_[h] + ed_lds[lo][h];
                e = (e > 0.f) ? e : 0.2f * e;
                pv[h] = __expf(e);
            }
            s_lds[j] = s;
            *(float4*)&p_lds[j * 8]     = make_float4(pv[0], pv[1], pv[2], pv[3]);
            *(float4*)&p_lds[j * 8 + 4] = make_float4(pv[4], pv[5], pv[6], pv[7]);
        }
    }
    __syncthreads();

    int lane = tid & 63;
    int wv = tid >> 6;
    int hd = lane >> 3;
    float sv0 = 0.f, sv1 = 0.f, sv2 = 0.f, sv3 = 0.f;
    float sq0 = 0.f, sq1 = 0.f, sq2 = 0.f, sq3 = 0.f;
    __half2 zero2 = __float2half2_rn(0.f);
#pragma unroll
    for (int t = 0; t < 2; ++t) {
        int nl = wv * 2 + t;
        int n = n0 + nl;
        int jb = rp_lds[nl] - beg0, je = rp_lds[nl + 1] - beg0;
        float den0 = 0.f, den1 = 0.f, den2 = 0.f, den3 = 0.f;
        __half2 c0l = zero2, c0h = zero2, c1l = zero2, c1h = zero2;
        __half2 c2l = zero2, c2h = zero2, c3l = zero2, c3h = zero2;
        int j = jb;
        if (staged) {
            for (; j + 3 < je; j += 4) {
                int s0 = s_lds[j], s1 = s_lds[j + 1], s2 = s_lds[j + 2], s3 = s_lds[j + 3];
                float p0 = p_lds[j * 8 + hd],       p1 = p_lds[(j + 1) * 8 + hd];
                float p2 = p_lds[(j + 2) * 8 + hd], p3 = p_lds[(j + 3) * 8 + hd];
                uint2 z0 = *(const uint2*)&z[(size_t)s0 * HH + lane * 4];
                uint2 z1 = *(const uint2*)&z[(size_t)s1 * HH + lane * 4];
                uint2 z2 = *(const uint2*)&z[(size_t)s2 * HH + lane * 4];
                uint2 z3 = *(const uint2*)&z[(size_t)s3 * HH + lane * 4];
                __half2 ph0 = __float2half2_rn(p0 * 0.0625f);
                __half2 ph1 = __float2half2_rn(p1 * 0.0625f);
                __half2 ph2 = __float2half2_rn(p2 * 0.0625f);
                __half2 ph3 = __float2half2_rn(p3 * 0.0625f);
                den0 += p0; den1 += p1; den2 += p2; den3 += p3;
                c0l = __hfma2(ph0, __builtin_bit_cast(__half2, z0.x), c0l);
                c0h = __hfma2(ph0, __builtin_bit_cast(__half2, z0.y), c0h);
                c1l = __hfma2(ph1, __builtin_bit_cast(__half2, z1.x), c1l);
                c1h = __hfma2(ph1, __builtin_bit_cast(__half2, z1.y), c1h);
                c2l = __hfma2(ph2, __builtin_bit_cast(__half2, z2.x), c2l);
                c2h = __hfma2(ph2, __builtin_bit_cast(__half2, z2.y), c2h);
                c3l = __hfma2(ph3, __builtin_bit_cast(__half2, z3.x), c3l);
                c3h = __hfma2(ph3, __builtin_bit_cast(__half2, z3.y), c3h);
            }
            for (; j < je; ++j) {
                int s0 = s_lds[j];
                float p0 = p_lds[j * 8 + hd];
                uint2 z0 = *(const uint2*)&z[(size_t)s0 * HH + lane * 4];
                __half2 ph0 = __float2half2_rn(p0 * 0.0625f);
                den0 += p0;
                c0l = __hfma2(ph0, __builtin_bit_cast(__half2, z0.x), c0l);
                c0h = __hfma2(ph0, __builtin_bit_cast(__half2, z0.y), c0h);
            }
        } else {   // fallback (astronomically rare): identical math from global
            float edv = ed_lds[nl][hd];
            for (; j < je; ++j) {
                int s0 = ssrc[beg0 + j];
                float e0 = esed[(size_t)s0 * 16 + hd] + edv;
                e0 = (e0 > 0.f) ? e0 : 0.2f * e0;
                float p0 = __expf(e0);
                uint2 z0 = *(const uint2*)&z[(size_t)s0 * HH + lane * 4];
                __half2 ph0 = __float2half2_rn(p0 * 0.0625f);
                den0 += p0;
                c0l = __hfma2(ph0, __builtin_bit_cast(__half2, z0.x), c0l);
                c0h = __hfma2(ph0, __builtin_bit_cast(__half2, z0.y), c0h);
            }
        }
        float den = (den0 + den1) + (den2 + den3);   // row nonempty (self loop)
        float inv = 16.f / den;
        float2 f0l = __half22float2(c0l), f1l = __half22float2(c1l);
        float2 f2l = __half22float2(c2l), f3l = __half22float2(c3l);
        float2 f0h = __half22float2(c0h), f1h = __half22float2(c1h);
        float2 f2h_ = __half22float2(c2h), f3h = __half22float2(c3h);
        ushort4 o;
        o.x = f2b(((f0l.x + f1l.x) + (f2l.x + f3l.x)) * inv);
        o.y = f2b(((f0l.y + f1l.y) + (f2l.y + f3l.y)) * inv);
        o.z = f2b(((f0h.x + f1h.x) + (f2h_.x + f3h.x)) * inv);
        o.w = f2b(((f0h.y + f1h.y) + (f2h_.y + f3h.y)) * inv);
        *(ushort4*)&outb[(size_t)n * HH + lane * 4] = o;
        float v0 = b2f(o.x), v1 = b2f(o.y), v2 = b2f(o.z), v3 = b2f(o.w);
        sv0 += v0; sv1 += v1; sv2 += v2; sv3 += v3;
        sq0 += v0 * v0; sq1 += v1 * v1; sq2 += v2 * v2; sq3 += v3 * v3;
    }
    // fused column stats: per-lane (4 channels) over 2 nodes -> LDS -> atomics
    ws[wv][lane][0] = sv0; ws[wv][lane][1] = sv1;
    ws[wv][lane][2] = sv2; ws[wv][lane][3] = sv3;
    ws[wv][lane][4] = sq0; ws[wv][lane][5] = sq1;
    ws[wv][lane][6] = sq2; ws[wv][lane][7] = sq3;
    __syncthreads();
    {
        int ll = tid & 63, jx = tid >> 6;     // jx 0..3
        float a = ws[0][ll][jx] + ws[1][ll][jx] + ws[2][ll][jx] + ws[3][ll][jx];
        float b = ws[0][ll][jx + 4] + ws[1][ll][jx + 4] + ws[2][ll][jx + 4] + ws[3][ll][jx + 4];
        atomicAdd(&sums[ll * 4 + jx], a);
        atomicAdd(&sums[HH + ll * 4 + jx], b);
    }
}

// ============================ final BN+ReLU+residual + output heads (fused) ============================
__global__ __launch_bounds__(256) void bn_out(const unsigned short* __restrict__ X,
                                              const float* __restrict__ sums,
                                              const float* __restrict__ gamma,
                                              const float* __restrict__ beta,
                                              const unsigned short* __restrict__ res,
                                              const float* __restrict__ mW,
                                              const float* __restrict__ mb,
                                              const float* __restrict__ lW,
                                              const float* __restrict__ lb,
                                              float* __restrict__ out) {
    int i = blockIdx.x * 256 + threadIdx.x;   // NN*64 threads exactly (12500 blocks)
    int row = i >> 6;
    int lane = threadIdx.x & 63;
    int c4 = (i & 63) * 4;
    const float invN = 1.f / NN;
    ushort4 u = *(const ushort4*)(X + (size_t)i * 4);
    float v0 = b2f(u.x), v1 = b2f(u.y), v2 = b2f(u.z), v3 = b2f(u.w);
    float4 s1 = *(const float4*)&sums[c4];
    float4 s2 = *(const float4*)&sums[HH + c4];
    float4 gm = *(const float4*)&gamma[c4];
    float4 bt = *(const float4*)&beta[c4];
    float mn0 = s1.x * invN, mn1 = s1.y * invN, mn2 = s1.z * invN, mn3 = s1.w * invN;
    float rs0 = rsqrtf(fmaxf(s2.x * invN - mn0 * mn0, 0.f) + 1e-5f);
    float rs1 = rsqrtf(fmaxf(s2.y * invN - mn1 * mn1, 0.f) + 1e-5f);
    float rs2 = rsqrtf(fmaxf(s2.z * invN - mn2 * mn2, 0.f) + 1e-5f);
    float rs3 = rsqrtf(fmaxf(s2.w * invN - mn3 * mn3, 0.f) + 1e-5f);
    float r0 = fmaxf((v0 - mn0) * rs0 * gm.x + bt.x, 0.f);
    float r1 = fmaxf((v1 - mn1) * rs1 * gm.y + bt.y, 0.f);
    float r2 = fmaxf((v2 - mn2) * rs2 * gm.z + bt.z, 0.f);
    float r3 = fmaxf((v3 - mn3) * rs3 * gm.w + bt.w, 0.f);
    ushort4 rv = *(const ushort4*)(res + (size_t)i * 4);
    r0 += b2f(rv.x); r1 += b2f(rv.y); r2 += b2f(rv.z); r3 += b2f(rv.w);
    float4 wv = *(const float4*)&mW[c4];
    float4 lv = *(const float4*)&lW[c4];
    float sm = r0 * wv.x + r1 * wv.y + r2 * wv.z + r3 * wv.w;
    float sl = r0 * lv.x + r1 * lv.y + r2 * lv.z + r3 * lv.w;
    for (int off = 32; off > 0; off >>= 1) {
        sm += __shfl_down(sm, off);
        sl += __shfl_down(sl, off);
    }
    if (lane == 0) {
        out[row] = sm + mb[0];
        float l2 = sl + lb[0];
        out[NN + row] = fminf(10.f, fmaxf(-10.f, l2));
    }
}

// ============================ launch ============================
extern "C" void kernel_launch(void* const* d_in, const int* in_sizes, int n_in,
                              void* d_out, int out_size, void* d_ws, size_t ws_size,
                              hipStream_t stream) {
    const float* x        = (const float*)d_in[0];
    const int*   ei       = (const int*)d_in[1];
    const float* in_W     = (const float*)d_in[2];
    const float* in_gamma = (const float*)d_in[4];
    const float* in_beta  = (const float*)d_in[5];
    const float* Ws       = (const float*)d_in[6];
    const float* att_src  = (const float*)d_in[7];
    const float* att_dst  = (const float*)d_in[8];
    const float* bn_gamma = (const float*)d_in[10];
    const float* bn_beta  = (const float*)d_in[11];
    const float* mean_W   = (const float*)d_in[12];
    const float* mean_b   = (const float*)d_in[13];
    const float* lv_W     = (const float*)d_in[14];
    const float* lv_b     = (const float*)d_in[15];
    float* out = (float*)d_out;

    // workspace layout (bytes)
    char* p = (char*)d_ws;
    unsigned short* z    = (unsigned short*)p; p += (size_t)NN * HH * 2;   // z (f16, row-major) for layers
    unsigned short* hb   = (unsigned short*)p; p += (size_t)NN * HH * 2;   // h (bf16); also raw input-proj z
    unsigned short* aggb = (unsigned short*)p; p += (size_t)NN * HH * 2;
    float* esed = (float*)p;                   p += (size_t)NN * 16 * 4;   // es|ed node-major
    float* sums0 = (float*)p;                  p += 512 * 4;
    float* sums1 = (float*)p;                  p += 512 * 4;
    unsigned short* WT   = (unsigned short*)p; p += (size_t)LL * HH * HH * 2;
    unsigned short* WaT  = (unsigned short*)p; p += (size_t)LL * 16 * HH * 2;
    unsigned short* inWT = (unsigned short*)p; p += (size_t)HH * 64 * 2;
    int* counts = (int*)p;                     p += (size_t)NN * 4;
    int* rowptr = (int*)p;                     p += (size_t)(NN + 1) * 4;
    int* cursor = (int*)p;                     p += (size_t)NN * 4;
    int* ssrc   = (int*)p;                     p += (size_t)ETOT * 4;
    int* bsums  = (int*)p;                     p += 64 * 4;
    unsigned short* xb = aggb;  // alias: xb dead before aggb first written

    // ---- CSR build (+ per-row source sort: locality + canonical order) ----
    hipMemsetAsync(counts, 0, NN * sizeof(int), stream);
    edge_hist<<<(ETOT + 255) / 256, 256, 0, stream>>>(ei, counts);
    scan1<<<SCAN_NBLK, 256, 0, stream>>>(counts, cursor, bsums);
    scan2<<<1, 64, 0, stream>>>(bsums);
    scan3<<<(NN + 255) / 256, 256, 0, stream>>>(cursor, bsums, counts, rowptr, cursor);
    edge_scatter<<<(ETOT + 255) / 256, 256, 0, stream>>>(ei, cursor, ssrc);
    sort_rows<<<(NN * 64 + 255) / 256, 256, 0, stream>>>(rowptr, ssrc);

    // ---- bf16 prep ----
    prep_wt<<<(LL * HH * HH + 255) / 256, 256, 0, stream>>>(Ws, WT);
    prep_wa<<<(LL * 16 * HH + 255) / 256, 256, 0, stream>>>(Ws, att_src, att_dst, WaT);
    prep_inwt<<<(HH * 64 + 255) / 256, 256, 0, stream>>>(in_W, inWT);
    prep_x<<<(NN * 64 + 255) / 256, 256, 0, stream>>>(x, xb);

    // ---- input projection -> hb (raw z) + fused column stats into sums0 ----
    hipMemsetAsync(sums0, 0, 512 * sizeof(float), stream);
    gemm_mfma<0><<<(NN + 127) / 128, 512, 0, stream>>>(xb, inWT, nullptr, hb,
                                                       nullptr, sums0, sums1,
                                                       nullptr, nullptr, nullptr,
                                                       nullptr, NN, 64);

    // ---- GAT layers: gemm applies previous stage's BN(+res) while staging A ----
    // stats double-buffer: aggregate_l -> (l&1)? sums0 : sums1; gemm zeroes it.
    for (int l = 0; l < LL; ++l) {
        const unsigned short* WTl = WT + (size_t)l * HH * HH;
        const unsigned short* WaTl = WaT + (size_t)l * 16 * HH;
        const unsigned short* bnX = (l == 0) ? hb : aggb;
        const unsigned short* resp = (l == 0) ? nullptr : hb;
        const float* gm = (l == 0) ? in_gamma : bn_gamma + (size_t)(l - 1) * HH;
        const float* bt = (l == 0) ? in_beta  : bn_beta  + (size_t)(l - 1) * HH;
        float* asums = (l & 1) ? sums0 : sums1;                       // aggregate_l writes
        float* rsums = (l == 0) ? sums0 : ((l & 1) ? sums1 : sums0);  // gemm_l reads

        gemm_mfma<1><<<(NN + 127) / 128, 512, 0, stream>>>(bnX, WTl, WaTl, z,
                                                           esed, rsums, asums,
                                                           gm, bt, resp, hb, NN, HH);
        aggregate<<<NN / 8, 256, 0, stream>>>(rowptr, ssrc, esed, z, aggb, asums);
    }

    // ---- final BN+ReLU+residual fused with output heads (aggregate_3 -> sums0) ----
    bn_out<<<(NN * 64) / 256, 256, 0, stream>>>(aggb, sums0, bn_gamma + 3 * HH,
                                                bn_beta + 3 * HH, hb,
                                                mean_W, mean_b, lv_W, lv_b, out);
}

// Round 19
// 597.141 us; speedup vs baseline: 4.6337x; 4.6337x over previous
//
#include <hip/hip_runtime.h>
#include <hip/hip_fp16.h>

#define NN 50000
#define EE 800000
#define ETOT 850000
#define KIN 61
#define HH 256
#define NH 8
#define CC 32
#define LL 4
#define SCAN_NBLK 49   // ceil(NN/1024)

typedef __attribute__((ext_vector_type(8))) short bf16x8;
typedef __attribute__((ext_vector_type(4))) float f32x4;

__device__ __forceinline__ unsigned short f2b(float f) {
    unsigned u = __builtin_bit_cast(unsigned, f);
    u += 0x7fffu + ((u >> 16) & 1u);   // RNE
    return (unsigned short)(u >> 16);
}
__device__ __forceinline__ float b2f(unsigned short h) {
    unsigned u = ((unsigned)h) << 16;
    return __builtin_bit_cast(float, u);
}
__device__ __forceinline__ unsigned short f2h(float f) {
    __half h = __float2half(f);        // RNE
    return __builtin_bit_cast(unsigned short, h);
}

// async global->LDS, 16B per lane; LDS dest is wave-uniform base + lane*16
__device__ __forceinline__ void gload16(const void* g, void* l) {
    __builtin_amdgcn_global_load_lds(
        (const __attribute__((address_space(1))) void*)g,
        (__attribute__((address_space(3))) void*)l, 16, 0, 0);
}

// ============================ CSR build ============================

__global__ __launch_bounds__(256) void edge_hist(const int* __restrict__ ei,
                                                 int* __restrict__ counts) {
    int e = blockIdx.x * 256 + threadIdx.x;
    if (e >= ETOT) return;
    int d = (e < EE) ? ei[EE + e] : (e - EE);
    atomicAdd(&counts[d], 1);
}

__global__ __launch_bounds__(256) void scan1(const int* __restrict__ counts,
                                             int* __restrict__ tmp,
                                             int* __restrict__ bsums) {
    __shared__ int lds[256];
    int b = blockIdx.x, t = threadIdx.x;
    int base = b * 1024 + t * 4;
    int v0 = 0, v1 = 0, v2 = 0, v3 = 0;
    if (base + 0 < NN) v0 = counts[base + 0];
    if (base + 1 < NN) v1 = counts[base + 1];
    if (base + 2 < NN) v2 = counts[base + 2];
    if (base + 3 < NN) v3 = counts[base + 3];
    int s = v0 + v1 + v2 + v3;
    lds[t] = s;
    __syncthreads();
    for (int off = 1; off < 256; off <<= 1) {
        int x = (t >= off) ? lds[t - off] : 0;
        __syncthreads();
        lds[t] += x;
        __syncthreads();
    }
    int run = lds[t] - s;
    if (t == 255) bsums[b] = lds[255];
    run += v0; if (base + 0 < NN) tmp[base + 0] = run;
    run += v1; if (base + 1 < NN) tmp[base + 1] = run;
    run += v2; if (base + 2 < NN) tmp[base + 2] = run;
    run += v3; if (base + 3 < NN) tmp[base + 3] = run;
}

// wave-parallel exclusive prefix over SCAN_NBLK block sums (1 wave)
__global__ void scan2(int* __restrict__ bsums) {
    int lane = threadIdx.x;                       // 64 threads
    int v = (lane < SCAN_NBLK) ? bsums[lane] : 0;
    int inc = v;
    for (int off = 1; off < 64; off <<= 1) {
        int t = __shfl_up(inc, off);
        if (lane >= off) inc += t;
    }
    if (lane < SCAN_NBLK) bsums[lane] = inc - v;  // exclusive
}

__global__ __launch_bounds__(256) void scan3(const int* __restrict__ tmp,
                                             const int* __restrict__ bsums,
                                             const int* __restrict__ counts,
                                             int* __restrict__ rowptr,
                                             int* __restrict__ cursor) {
    int i = blockIdx.x * 256 + threadIdx.x;
    if (i >= NN) return;
    int incl = tmp[i] + bsums[i >> 10];
    rowptr[i + 1] = incl;
    cursor[i] = incl - counts[i];
    if (i == 0) rowptr[0] = 0;
}

__global__ __launch_bounds__(256) void edge_scatter(const int* __restrict__ ei,
                                                    int* __restrict__ cursor,
                                                    int* __restrict__ ssrc) {
    int e = blockIdx.x * 256 + threadIdx.x;
    if (e >= ETOT) return;
    int s, d;
    if (e < EE) { s = ei[e]; d = ei[EE + e]; } else { s = d = e - EE; }
    int pos = atomicAdd(&cursor[d], 1);
    ssrc[pos] = s;
}

// sort each row's sources ascending (deterministic 64-lane bitonic).
__global__ __launch_bounds__(256) void sort_rows(const int* __restrict__ rowptr,
                                                 int* __restrict__ ssrc) {
    int wid = (blockIdx.x * 256 + threadIdx.x) >> 6;
    int lane = threadIdx.x & 63;
    if (wid >= NN) return;
    int beg = rowptr[wid], end = rowptr[wid + 1];
    int L = end - beg;
    if (L > 64) return;
    int v = (lane < L) ? ssrc[beg + lane] : 0x7fffffff;
#pragma unroll
    for (int k = 2; k <= 64; k <<= 1) {
#pragma unroll
        for (int j = k >> 1; j > 0; j >>= 1) {
            int partner = __shfl_xor(v, j);
            bool up = ((lane & k) == 0);
            bool keepMin = (up == ((lane & j) == 0));
            int mn = min(v, partner), mx = max(v, partner);
            v = keepMin ? mn : mx;
        }
    }
    if (lane < L) ssrc[beg + lane] = v;
}

// ============================ weight / input prep (bf16) ============================

__global__ __launch_bounds__(256) void prep_wt(const float* __restrict__ Ws,
                                               unsigned short* __restrict__ WT) {
    int t = blockIdx.x * 256 + threadIdx.x;
    if (t >= LL * HH * HH) return;
    int l = t >> 16, rem = t & 65535;
    int n = rem >> 8, k = rem & 255;
    WT[t] = f2b(Ws[l * 65536 + k * HH + n]);
}

// WaT[l][oc][k] = bf16( sum_c W[k][hd*32+c] * a[hd][c] ), oc<8: att_src, else att_dst.
__global__ __launch_bounds__(256) void prep_wa(const float* __restrict__ Ws,
                                               const float* __restrict__ att_src,
                                               const float* __restrict__ att_dst,
                                               unsigned short* __restrict__ WaT) {
    int t = blockIdx.x * 256 + threadIdx.x;
    if (t >= LL * 16 * 256) return;
    int l = t >> 12, rem = t & 4095;
    int oc = rem >> 8, k = rem & 255;
    int hd = oc & 7;
    const float* a = ((oc < 8) ? att_src : att_dst) + ((size_t)l * NH + hd) * CC;
    const float* Wl = Ws + (size_t)l * 65536 + (size_t)k * HH + hd * CC;
    float s = 0.f;
#pragma unroll
    for (int c = 0; c < CC; ++c) s += Wl[c] * a[c];
    WaT[t] = f2b(s);
}

__global__ __launch_bounds__(256) void prep_inwt(const float* __restrict__ in_W,
                                                 unsigned short* __restrict__ WT) {
    int t = blockIdx.x * 256 + threadIdx.x;
    if (t >= HH * 64) return;
    int n = t >> 6, k = t & 63;
    WT[t] = (k < KIN) ? f2b(in_W[k * HH + n]) : 0;
}

__global__ __launch_bounds__(256) void prep_x(const float* __restrict__ x,
                                              unsigned short* __restrict__ xb) {
    int t = blockIdx.x * 256 + threadIdx.x;
    if (t >= NN * 64) return;
    int n = t >> 6, c = t & 63;
    xb[t] = (c < KIN) ? f2b(x[n * KIN + c]) : 0;
}

// ============================ MFMA GEMM (+ fused BN + attn-score columns) ============================
// tile 128 rows x 256(+16) cols x 64 K, 8 waves (512 thr) arranged 2(wm) x 4(wn).
// MODE 0: A via gload16, C row-major bf16 + fused column stats (atomicAdd sums).
// MODE 1: A = relu(bn(bnX)) [+res] built during staging (also written to hbNew);
//   C = head-major f16 zT; Bs rows 256..271 hold WaT -> waves wn==0 compute
//   es/ed as extra MFMA columns (accX), stored directly to esrcT/edstT.
// BOTH: zero zsums (next stage's stats buffer) -- deletes memset dispatches.
template<int MODE>
__global__ __launch_bounds__(512) void gemm_mfma(const unsigned short* __restrict__ Asrc,
                                                 const unsigned short* __restrict__ Bt,
                                                 const unsigned short* __restrict__ WaTl,
                                                 unsigned short* __restrict__ C,
                                                 float* __restrict__ esrcT,
                                                 float* __restrict__ edstT,
                                                 float* __restrict__ sums,
                                                 float* __restrict__ zsums,
                                                 const float* __restrict__ gamma,
                                                 const float* __restrict__ beta,
                                                 const unsigned short* __restrict__ res,
                                                 unsigned short* __restrict__ hbNew,
                                                 int M, int K) {
    __shared__ unsigned short As[128 * 64];   // 16 KB
    __shared__ unsigned short Bs[272 * 64];   // 34 KB (rows 256..271 = Wa cols)
    __shared__ float scaleS[256], shiftS[256];
    int row0 = blockIdx.x * 128;
    int tid = threadIdx.x;
    int w = tid >> 6, l = tid & 63;
    int wm = w >> 2, wn = w & 3;
    int r15 = l & 15, q = l >> 4;

    if (tid < 256) {                      // all blocks write 0: idempotent
        zsums[tid] = 0.f;
        zsums[HH + tid] = 0.f;
    }
    if constexpr (MODE == 1) {
        if (tid < 256) {
            const float invN = 1.f / NN;
            float mn = sums[tid] * invN;
            float var = fmaxf(sums[256 + tid] * invN - mn * mn, 0.f);
            float rs = rsqrtf(var + 1e-5f);
            float sc = rs * gamma[tid];
            scaleS[tid] = sc;
            shiftS[tid] = beta[tid] - mn * sc;
        }
        __syncthreads();
    }

    f32x4 acc[4][4] = {};
    f32x4 accX[4] = {};          // es/ed columns (used by wn==0 waves)

    int crow = l >> 3;     // row within 8-row chunk
    int cs   = l & 7;      // 16B slot within row

    for (int kt = 0; kt < K; kt += 64) {
        if (kt) __syncthreads();
        // stage A: wave w covers rows w*16 .. w*16+15 (2 chunks of 8)
#pragma unroll
        for (int c = 0; c < 2; ++c) {
            int r = w * 16 + c * 8 + crow;          // 0..127
            int sg = cs ^ (r & 7);                  // pre-swizzled source slot
            int ga = row0 + r;
            if constexpr (MODE == 0) {
                if (ga >= M) ga = M - 1;
                gload16(&Asrc[(size_t)ga * K + kt + sg * 8], &As[(w * 16 + c * 8) * 64]);
            } else {
                unsigned short* dst = &As[(w * 16 + c * 8) * 64 + l * 8];
                if (ga < M) {
                    int ch = kt + sg * 8;
                    ushort4 xlo = *(const ushort4*)&Asrc[(size_t)ga * 256 + ch];
                    ushort4 xhi = *(const ushort4*)&Asrc[(size_t)ga * 256 + ch + 4];
                    float4 sc0 = *(const float4*)&scaleS[ch];
                    float4 sc1 = *(const float4*)&scaleS[ch + 4];
                    float4 sh0 = *(const float4*)&shiftS[ch];
                    float4 sh1 = *(const float4*)&shiftS[ch + 4];
                    float f0 = fmaxf(b2f(xlo.x) * sc0.x + sh0.x, 0.f);
                    float f1 = fmaxf(b2f(xlo.y) * sc0.y + sh0.y, 0.f);
                    float f2 = fmaxf(b2f(xlo.z) * sc0.z + sh0.z, 0.f);
                    float f3 = fmaxf(b2f(xlo.w) * sc0.w + sh0.w, 0.f);
                    float f4 = fmaxf(b2f(xhi.x) * sc1.x + sh1.x, 0.f);
                    float f5 = fmaxf(b2f(xhi.y) * sc1.y + sh1.y, 0.f);
                    float f6 = fmaxf(b2f(xhi.z) * sc1.z + sh1.z, 0.f);
                    float f7 = fmaxf(b2f(xhi.w) * sc1.w + sh1.w, 0.f);
                    if (res) {
                        ushort4 rlo = *(const ushort4*)&res[(size_t)ga * 256 + ch];
                        ushort4 rhi = *(const ushort4*)&res[(size_t)ga * 256 + ch + 4];
                        f0 += b2f(rlo.x); f1 += b2f(rlo.y); f2 += b2f(rlo.z); f3 += b2f(rlo.w);
                        f4 += b2f(rhi.x); f5 += b2f(rhi.y); f6 += b2f(rhi.z); f7 += b2f(rhi.w);
                    }
                    ushort4 olo, ohi;
                    olo.x = f2b(f0); olo.y = f2b(f1); olo.z = f2b(f2); olo.w = f2b(f3);
                    ohi.x = f2b(f4); ohi.y = f2b(f5); ohi.z = f2b(f6); ohi.w = f2b(f7);
                    *(ushort4*)dst = olo;
                    *(ushort4*)(dst + 4) = ohi;
                    *(ushort4*)&hbNew[(size_t)ga * 256 + ch] = olo;
                    *(ushort4*)&hbNew[(size_t)ga * 256 + ch + 4] = ohi;
                } else {
                    ushort4 zz = {0, 0, 0, 0};
                    *(ushort4*)dst = zz;
                    *(ushort4*)(dst + 4) = zz;
                }
            }
        }
        // stage B: wave w stages rows w*32 .. w*32+31 (4 chunks of 8)
#pragma unroll
        for (int c = 0; c < 4; ++c) {
            int r = w * 32 + c * 8 + crow;          // 0..255
            int sg = cs ^ (r & 7);
            gload16(&Bt[(size_t)r * K + kt + sg * 8], &Bs[(w * 32 + c * 8) * 64]);
        }
        if constexpr (MODE == 1) {
            // stage Wa rows 256..271 (waves 0,1; one 8-row chunk each)
            if (w < 2) {
                int rr = w * 8 + crow;              // 0..15
                int sg = cs ^ (crow & 7);           // (256+rr)&7 == crow
                gload16(&WaTl[(size_t)rr * K + kt + sg * 8], &Bs[(256 + w * 8) * 64]);
            }
        }
        __syncthreads();
#pragma unroll
        for (int kk = 0; kk < 2; ++kk) {
            bf16x8 aF[4], bF[4];
#pragma unroll
            for (int i = 0; i < 4; ++i) {
                int ar = wm * 64 + i * 16 + r15;
                aF[i] = *(bf16x8*)&As[ar * 64 + ((kk * 4 + q) ^ (ar & 7)) * 8];
                int br = wn * 64 + i * 16 + r15;
                bF[i] = *(bf16x8*)&Bs[br * 64 + ((kk * 4 + q) ^ (br & 7)) * 8];
            }
#pragma unroll
            for (int i = 0; i < 4; ++i)
#pragma unroll
                for (int j = 0; j < 4; ++j)
                    acc[i][j] = __builtin_amdgcn_mfma_f32_16x16x32_bf16(aF[i], bF[j], acc[i][j], 0, 0, 0);
            if constexpr (MODE == 1) {
                if (wn == 0) {
                    int br = 256 + r15;
                    bf16x8 bX = *(bf16x8*)&Bs[br * 64 + ((kk * 4 + q) ^ (br & 7)) * 8];
#pragma unroll
                    for (int i = 0; i < 4; ++i)
                        accX[i] = __builtin_amdgcn_mfma_f32_16x16x32_bf16(aF[i], bX, accX[i], 0, 0, 0);
                }
            }
        }
    }

    // C/D layout: col = lane&15, row = (lane>>4)*4 + reg
#pragma unroll
    for (int i = 0; i < 4; ++i)
#pragma unroll
        for (int j = 0; j < 4; ++j) {
            int nc = wn * 64 + j * 16 + r15;
#pragma unroll
            for (int r = 0; r < 4; ++r) {
                int gr = row0 + wm * 64 + i * 16 + q * 4 + r;
                if (gr < M) {
                    if (MODE == 1)
                        C[(size_t)(nc >> 5) * NN * CC + (size_t)gr * CC + (nc & 31)] = f2h(acc[i][j][r]);
                    else
                        C[(size_t)gr * HH + nc] = f2b(acc[i][j][r]);
                }
            }
        }

    if constexpr (MODE == 1) {
        // attn scores: accX cols 0..7 = es(head), 8..15 = ed(head). Direct stores.
        if (wn == 0) {
            int hd = r15 & 7;
            float* dstp = (r15 < 8) ? esrcT : edstT;
#pragma unroll
            for (int i = 0; i < 4; ++i)
#pragma unroll
                for (int r = 0; r < 4; ++r) {
                    int gr = row0 + wm * 64 + i * 16 + q * 4 + r;
                    if (gr < M) dstp[(size_t)hd * NN + gr] = accX[i][r];
                }
        }
    } else {
        // fused column stats over this block's valid rows (rounded values)
#pragma unroll
        for (int j = 0; j < 4; ++j) {
            float v = 0.f, qq = 0.f;
#pragma unroll
            for (int i = 0; i < 4; ++i)
#pragma unroll
                for (int r = 0; r < 4; ++r) {
                    int gr = row0 + wm * 64 + i * 16 + q * 4 + r;
                    if (gr < M) {
                        float f = b2f(f2b(acc[i][j][r]));
                        v += f; qq += f * f;
                    }
                }
            v += __shfl_xor(v, 16); qq += __shfl_xor(qq, 16);
            v += __shfl_xor(v, 32); qq += __shfl_xor(qq, 32);
            if (q == 0) {
                int nc = wn * 64 + j * 16 + r15;
                atomicAdd(&sums[nc], v);
                atomicAdd(&sums[HH + nc], qq);
            }
        }
    }
}

// ============================ head-affine aggregate v9 (FROZEN; packed-f16 phase B) ============================
// blockIdx.x & 7 == head -> round-robin dispatch pins head hd's z-slice (3.2MB)
// + esrcT slice (200KB) in ONE XCD's 4MB L2. Block = 32 nodes x 1 head.
// Phase A: stage (s, p=exp(leaky(es+ed))) in LDS. Phase B: 8-lane group per
// node; per edge: 8B f16 z load + broadcast-packed p/16 + 2x v_pk_fma_f16,
// 4 banks. Epilogue: fused per-block column stats.
#define MAXEB 2048   // max staged edges per 32-node block (rows <= 64 each)
__global__ __launch_bounds__(256) void aggregate(const int* __restrict__ rowptr,
                                                 const int* __restrict__ ssrc,
                                                 const float* __restrict__ esrcT,
                                                 const float* __restrict__ edstT,
                                                 const unsigned short* __restrict__ zT,
                                                 unsigned short* __restrict__ outb,
                                                 float* __restrict__ sums) {
    __shared__ int   s_lds[MAXEB];
    __shared__ float p_lds[MAXEB];
    __shared__ int   rp_lds[33];
    __shared__ float ed_lds[32];
    __shared__ float ws1[4][8][4], ws2[4][8][4];
    int bid = blockIdx.x;
    int hd = bid & 7;
    int n0 = (bid >> 3) * 32;
    int tid = threadIdx.x;
    const float* esp = esrcT + (size_t)hd * NN;
    const unsigned short* zp = zT + (size_t)hd * NN * CC;

    if (tid <= 32) {
        int idx = n0 + tid;
        rp_lds[tid] = rowptr[idx > NN ? NN : idx];
    }
    if (tid < 32) {
        int nn = n0 + tid;
        ed_lds[tid] = (nn < NN) ? edstT[(size_t)hd * NN + nn] : 0.f;
    }
    __syncthreads();
    int beg0 = rp_lds[0];
    int total = rp_lds[32] - beg0;
    bool staged = (total <= MAXEB);
    if (staged) {
        for (int j = tid; j < total; j += 256) {
            int s = ssrc[beg0 + j];
            int jj = beg0 + j;
            int lo = 0, hi = 32;
#pragma unroll
            for (int st = 0; st < 5; ++st) {
                int mid = (lo + hi) >> 1;
                bool le = (rp_lds[mid] <= jj);
                lo = le ? mid : lo;
                hi = le ? hi : mid;
            }
            float e = esp[s] + ed_lds[lo];
            e = (e > 0.f) ? e : 0.2f * e;
            s_lds[j] = s;
            p_lds[j] = __expf(e);
        }
    }
    __syncthreads();

    int lane = tid & 63;
    int wv = tid >> 6;
    int g = lane >> 3;
    int nl = wv * 8 + g;                            // local node 0..31
    int n = n0 + nl;
    int col = (lane & 7) * 4;
    bool act = n < NN;
    int jbeg = rp_lds[nl] - beg0;
    int jend = rp_lds[nl + 1] - beg0;

    float d0 = 0.f, d1 = 0.f, d2 = 0.f, d3 = 0.f;
    __half2 zero2 = __float2half2_rn(0.f);
    __half2 c0l = zero2, c0h = zero2, c1l = zero2, c1h = zero2;
    __half2 c2l = zero2, c2h = zero2, c3l = zero2, c3h = zero2;
    int j = jbeg;
    if (staged) {
        for (; j + 3 < jend; j += 4) {
            int s0 = s_lds[j], s1 = s_lds[j + 1], s2 = s_lds[j + 2], s3 = s_lds[j + 3];
            float p0 = p_lds[j], p1 = p_lds[j + 1], p2 = p_lds[j + 2], p3 = p_lds[j + 3];
            uint2 z0 = *(const uint2*)&zp[(size_t)(s0 * CC + col)];
            uint2 z1 = *(const uint2*)&zp[(size_t)(s1 * CC + col)];
            uint2 z2 = *(const uint2*)&zp[(size_t)(s2 * CC + col)];
            uint2 z3 = *(const uint2*)&zp[(size_t)(s3 * CC + col)];
            __half2 ph0 = __float2half2_rn(p0 * 0.0625f);
            __half2 ph1 = __float2half2_rn(p1 * 0.0625f);
            __half2 ph2 = __float2half2_rn(p2 * 0.0625f);
            __half2 ph3 = __float2half2_rn(p3 * 0.0625f);
            d0 += p0; d1 += p1; d2 += p2; d3 += p3;
            c0l = __hfma2(ph0, __builtin_bit_cast(__half2, z0.x), c0l);
            c0h = __hfma2(ph0, __builtin_bit_cast(__half2, z0.y), c0h);
            c1l = __hfma2(ph1, __builtin_bit_cast(__half2, z1.x), c1l);
            c1h = __hfma2(ph1, __builtin_bit_cast(__half2, z1.y), c1h);
            c2l = __hfma2(ph2, __builtin_bit_cast(__half2, z2.x), c2l);
            c2h = __hfma2(ph2, __builtin_bit_cast(__half2, z2.y), c2h);
            c3l = __hfma2(ph3, __builtin_bit_cast(__half2, z3.x), c3l);
            c3h = __hfma2(ph3, __builtin_bit_cast(__half2, z3.y), c3h);
        }
        for (; j < jend; ++j) {
            int s0 = s_lds[j];
            float p0 = p_lds[j];
            uint2 z0 = *(const uint2*)&zp[(size_t)(s0 * CC + col)];
            __half2 ph0 = __float2half2_rn(p0 * 0.0625f);
            d0 += p0;
            c0l = __hfma2(ph0, __builtin_bit_cast(__half2, z0.x), c0l);
            c0h = __hfma2(ph0, __builtin_bit_cast(__half2, z0.y), c0h);
        }
    } else {   // fallback (astronomically rare): identical f16 math from global
        float ed = act ? ed_lds[nl] : 0.f;
        for (; j < jend; ++j) {
            int s0 = ssrc[beg0 + j];
            float es0 = esp[s0];
            uint2 z0 = *(const uint2*)&zp[(size_t)(s0 * CC + col)];
            float e0 = es0 + ed; e0 = (e0 > 0.f) ? e0 : 0.2f * e0;
            float p0 = __expf(e0);
            __half2 ph0 = __float2half2_rn(p0 * 0.0625f);
            d0 += p0;
            c0l = __hfma2(ph0, __builtin_bit_cast(__half2, z0.x), c0l);
            c0h = __hfma2(ph0, __builtin_bit_cast(__half2, z0.y), c0h);
        }
    }
    float v0 = 0.f, v1 = 0.f, v2 = 0.f, v3 = 0.f;
    if (act) {
        float den = (d0 + d1) + (d2 + d3);          // row nonempty (self loop)
        float inv = 16.f / den;
        float2 f0l = __half22float2(c0l), f1l = __half22float2(c1l);
        float2 f2l = __half22float2(c2l), f3l = __half22float2(c3l);
        float2 f0h = __half22float2(c0h), f1h = __half22float2(c1h);
        float2 f2h_ = __half22float2(c2h), f3h = __half22float2(c3h);
        ushort4 o;
        o.x = f2b(((f0l.x + f1l.x) + (f2l.x + f3l.x)) * inv);
        o.y = f2b(((f0l.y + f1l.y) + (f2l.y + f3l.y)) * inv);
        o.z = f2b(((f0h.x + f1h.x) + (f2h_.x + f3h.x)) * inv);
        o.w = f2b(((f0h.y + f1h.y) + (f2h_.y + f3h.y)) * inv);
        *(ushort4*)&outb[(size_t)n * HH + hd * CC + col] = o;
        v0 = b2f(o.x); v1 = b2f(o.y); v2 = b2f(o.z); v3 = b2f(o.w);
    }
    // fused column stats over this block's 32 nodes (rounded values)
    float q0 = v0 * v0, q1 = v1 * v1, q2 = v2 * v2, q3 = v3 * v3;
#pragma unroll
    for (int off = 8; off <= 32; off <<= 1) {
        v0 += __shfl_xor(v0, off); v1 += __shfl_xor(v1, off);
        v2 += __shfl_xor(v2, off); v3 += __shfl_xor(v3, off);
        q0 += __shfl_xor(q0, off); q1 += __shfl_xor(q1, off);
        q2 += __shfl_xor(q2, off); q3 += __shfl_xor(q3, off);
    }
    if (g == 0) {
        int slot = lane & 7;
        ws1[wv][slot][0] = v0; ws1[wv][slot][1] = v1;
        ws1[wv][slot][2] = v2; ws1[wv][slot][3] = v3;
        ws2[wv][slot][0] = q0; ws2[wv][slot][1] = q1;
        ws2[wv][slot][2] = q2; ws2[wv][slot][3] = q3;
    }
    __syncthreads();
    if (tid < 32) {
        int slot = tid & 7, k = tid >> 3;
        float s1v = ws1[0][slot][k] + ws1[1][slot][k] + ws1[2][slot][k] + ws1[3][slot][k];
        float s2v = ws2[0][slot][k] + ws2[1][slot][k] + ws2[2][slot][k] + ws2[3][slot][k];
        int ch = hd * CC + slot * 4 + k;
        atomicAdd(&sums[ch], s1v);
        atomicAdd(&sums[HH + ch], s2v);
    }
}

// ============================ final BN+ReLU+residual + output heads (fused) ============================
__global__ __launch_bounds__(256) void bn_out(const unsigned short* __restrict__ X,
                                              const float* __restrict__ sums,
                                              const float* __restrict__ gamma,
                                              const float* __restrict__ beta,
                                              const unsigned short* __restrict__ res,
                                              const float* __restrict__ mW,
                                              const float* __restrict__ mb,
                                              const float* __restrict__ lW,
                                              const float* __restrict__ lb,
                                              float* __restrict__ out) {
    int i = blockIdx.x * 256 + threadIdx.x;   // NN*64 threads exactly (12500 blocks)
    int row = i >> 6;
    int lane = threadIdx.x & 63;
    int c4 = (i & 63) * 4;
    const float invN = 1.f / NN;
    ushort4 u = *(const ushort4*)(X + (size_t)i * 4);
    float v0 = b2f(u.x), v1 = b2f(u.y), v2 = b2f(u.z), v3 = b2f(u.w);
    float4 s1 = *(const float4*)&sums[c4];
    float4 s2 = *(const float4*)&sums[HH + c4];
    float4 gm = *(const float4*)&gamma[c4];
    float4 bt = *(const float4*)&beta[c4];
    float mn0 = s1.x * invN, mn1 = s1.y * invN, mn2 = s1.z * invN, mn3 = s1.w * invN;
    float rs0 = rsqrtf(fmaxf(s2.x * invN - mn0 * mn0, 0.f) + 1e-5f);
    float rs1 = rsqrtf(fmaxf(s2.y * invN - mn1 * mn1, 0.f) + 1e-5f);
    float rs2 = rsqrtf(fmaxf(s2.z * invN - mn2 * mn2, 0.f) + 1e-5f);
    float rs3 = rsqrtf(fmaxf(s2.w * invN - mn3 * mn3, 0.f) + 1e-5f);
    float r0 = fmaxf((v0 - mn0) * rs0 * gm.x + bt.x, 0.f);
    float r1 = fmaxf((v1 - mn1) * rs1 * gm.y + bt.y, 0.f);
    float r2 = fmaxf((v2 - mn2) * rs2 * gm.z + bt.z, 0.f);
    float r3 = fmaxf((v3 - mn3) * rs3 * gm.w + bt.w, 0.f);
    ushort4 rv = *(const ushort4*)(res + (size_t)i * 4);
    r0 += b2f(rv.x); r1 += b2f(rv.y); r2 += b2f(rv.z); r3 += b2f(rv.w);
    float4 wv = *(const float4*)&mW[c4];
    float4 lv = *(const float4*)&lW[c4];
    float sm = r0 * wv.x + r1 * wv.y + r2 * wv.z + r3 * wv.w;
    float sl = r0 * lv.x + r1 * lv.y + r2 * lv.z + r3 * lv.w;
    for (int off = 32; off > 0; off >>= 1) {
        sm += __shfl_down(sm, off);
        sl += __shfl_down(sl, off);
    }
    if (lane == 0) {
        out[row] = sm + mb[0];
        float l2 = sl + lb[0];
        out[NN + row] = fminf(10.f, fmaxf(-10.f, l2));
    }
}

// ============================ launch ============================
extern "C" void kernel_launch(void* const* d_in, const int* in_sizes, int n_in,
                              void* d_out, int out_size, void* d_ws, size_t ws_size,
                              hipStream_t stream) {
    const float* x        = (const float*)d_in[0];
    const int*   ei       = (const int*)d_in[1];
    const float* in_W     = (const float*)d_in[2];
    const float* in_gamma = (const float*)d_in[4];
    const float* in_beta  = (const float*)d_in[5];
    const float* Ws       = (const float*)d_in[6];
    const float* att_src  = (const float*)d_in[7];
    const float* att_dst  = (const float*)d_in[8];
    const float* bn_gamma = (const float*)d_in[10];
    const float* bn_beta  = (const float*)d_in[11];
    const float* mean_W   = (const float*)d_in[12];
    const float* mean_b   = (const float*)d_in[13];
    const float* lv_W     = (const float*)d_in[14];
    const float* lv_b     = (const float*)d_in[15];
    float* out = (float*)d_out;

    // workspace layout (bytes)
    char* p = (char*)d_ws;
    unsigned short* z    = (unsigned short*)p; p += (size_t)NN * HH * 2;   // zT (f16) for layers
    unsigned short* hb   = (unsigned short*)p; p += (size_t)NN * HH * 2;   // h (bf16); also raw input-proj z
    unsigned short* aggb = (unsigned short*)p; p += (size_t)NN * HH * 2;
    float* esrcT = (float*)p;                  p += (size_t)NN * NH * 4;
    float* edstT = (float*)p;                  p += (size_t)NN * NH * 4;
    float* sums0 = (float*)p;                  p += 512 * 4;
    float* sums1 = (float*)p;                  p += 512 * 4;
    unsigned short* WT   = (unsigned short*)p; p += (size_t)LL * HH * HH * 2;
    unsigned short* WaT  = (unsigned short*)p; p += (size_t)LL * 16 * HH * 2;
    unsigned short* inWT = (unsigned short*)p; p += (size_t)HH * 64 * 2;
    int* counts = (int*)p;                     p += (size_t)NN * 4;
    int* rowptr = (int*)p;                     p += (size_t)(NN + 1) * 4;
    int* cursor = (int*)p;                     p += (size_t)NN * 4;
    int* ssrc   = (int*)p;                     p += (size_t)ETOT * 4;
    int* bsums  = (int*)p;                     p += 64 * 4;
    unsigned short* xb = aggb;  // alias: xb dead before aggb first written

    // ---- CSR build (+ per-row source sort: locality + canonical order) ----
    hipMemsetAsync(counts, 0, NN * sizeof(int), stream);
    edge_hist<<<(ETOT + 255) / 256, 256, 0, stream>>>(ei, counts);
    scan1<<<SCAN_NBLK, 256, 0, stream>>>(counts, cursor, bsums);
    scan2<<<1, 64, 0, stream>>>(bsums);
    scan3<<<(NN + 255) / 256, 256, 0, stream>>>(cursor, bsums, counts, rowptr, cursor);
    edge_scatter<<<(ETOT + 255) / 256, 256, 0, stream>>>(ei, cursor, ssrc);
    sort_rows<<<(NN * 64 + 255) / 256, 256, 0, stream>>>(rowptr, ssrc);

    // ---- bf16 prep ----
    prep_wt<<<(LL * HH * HH + 255) / 256, 256, 0, stream>>>(Ws, WT);
    prep_wa<<<(LL * 16 * HH + 255) / 256, 256, 0, stream>>>(Ws, att_src, att_dst, WaT);
    prep_inwt<<<(HH * 64 + 255) / 256, 256, 0, stream>>>(in_W, inWT);
    prep_x<<<(NN * 64 + 255) / 256, 256, 0, stream>>>(x, xb);

    // ---- input projection -> hb (raw z) + fused column stats into sums0 ----
    hipMemsetAsync(sums0, 0, 512 * sizeof(float), stream);
    gemm_mfma<0><<<(NN + 127) / 128, 512, 0, stream>>>(xb, inWT, nullptr, hb,
                                                       nullptr, nullptr, sums0, sums1,
                                                       nullptr, nullptr, nullptr,
                                                       nullptr, NN, 64);

    // ---- GAT layers: gemm applies previous stage's BN(+res) while staging A ----
    // stats double-buffer: aggregate_l -> (l&1)? sums0 : sums1; gemm zeroes it.
    for (int l = 0; l < LL; ++l) {
        const unsigned short* WTl = WT + (size_t)l * HH * HH;
        const unsigned short* WaTl = WaT + (size_t)l * 16 * HH;
        const unsigned short* bnX = (l == 0) ? hb : aggb;
        const unsigned short* resp = (l == 0) ? nullptr : hb;
        const float* gm = (l == 0) ? in_gamma : bn_gamma + (size_t)(l - 1) * HH;
        const float* bt = (l == 0) ? in_beta  : bn_beta  + (size_t)(l - 1) * HH;
        float* asums = (l & 1) ? sums0 : sums1;                       // aggregate_l writes
        float* rsums = (l == 0) ? sums0 : ((l & 1) ? sums1 : sums0);  // gemm_l reads

        gemm_mfma<1><<<(NN + 127) / 128, 512, 0, stream>>>(bnX, WTl, WaTl, z,
                                                           esrcT, edstT, rsums, asums,
                                                           gm, bt, resp, hb, NN, HH);
        aggregate<<<((NN + 31) / 32) * 8, 256, 0, stream>>>(rowptr, ssrc, esrcT, edstT,
                                                            z, aggb, asums);
    }

    // ---- final BN+ReLU+residual fused with output heads (aggregate_3 -> sums0) ----
    bn_out<<<(NN * 64) / 256, 256, 0, stream>>>(aggb, sums0, bn_gamma + 3 * HH,
                                                bn_beta + 3 * HH, hb,
                                                mean_W, mean_b, lv_W, lv_b, out);
}